// Round 10
// baseline (465.217 us; speedup 1.0000x reference)
//
#include <hip/hip_runtime.h>

typedef unsigned short u16;
typedef __attribute__((ext_vector_type(8))) short short8;   // 8 bf16 = 4 VGPRs
typedef __attribute__((ext_vector_type(4))) float floatx4;

__device__ __forceinline__ float bf2f(u16 u) {
  union { unsigned int i; float f; } v; v.i = ((unsigned int)u) << 16; return v.f;
}
__device__ __forceinline__ u16 f2bf(float f) {
  union { float f; unsigned int i; } v; v.f = f;
  unsigned int u = v.i;
  u += 0x7fffu + ((u >> 16) & 1u);   // RNE
  return (u16)(u >> 16);
}

__device__ __forceinline__ void gld_lds16(const void* g, void* l) {
  __builtin_amdgcn_global_load_lds(
      (const __attribute__((address_space(1))) unsigned int*)g,
      (__attribute__((address_space(3))) unsigned int*)l, 16, 0, 0);
}

#define SBAR()   __builtin_amdgcn_s_barrier()
#define SCHED0() __builtin_amdgcn_sched_barrier(0)

// ---------------------------------------------------------------------------
// One-shot repack: blockIdx.y selects region.
//  0: x      [4096,2048] -> xb
//  1: wcat   rows 0..1535 wq_a, 1536..2111 wkv_a, 2112..2175 zero  (cols 2048)
//  2: wq_b   [3072,1536] -> wqbb
//  3: wkv_b  [4096,512]  -> wkbb
//  4: wo     [2048,2048] -> wob
// ---------------------------------------------------------------------------
__global__ __launch_bounds__(256) void repack_all_k(
    const float* __restrict__ x, const float* __restrict__ wqa,
    const float* __restrict__ wkva, const float* __restrict__ wqb,
    const float* __restrict__ wkvb, const float* __restrict__ wo,
    u16* __restrict__ xb, u16* __restrict__ wcat, u16* __restrict__ wqbb,
    u16* __restrict__ wkbb, u16* __restrict__ wob) {
  long i = ((long)blockIdx.x * 256 + threadIdx.x) * 4;
  int region = blockIdx.y;
  const float* s = nullptr; u16* d = nullptr; long n = 0;
  switch (region) {
    case 0: s = x;    d = xb;   n = 4096L * 2048; break;
    case 1: s = nullptr; d = wcat; n = 2176L * 2048; break;
    case 2: s = wqb;  d = wqbb; n = 3072L * 1536; break;
    case 3: s = wkvb; d = wkbb; n = 4096L * 512;  break;
    case 4: s = wo;   d = wob;  n = 2048L * 2048; break;
  }
  if (i >= n) return;
  float4 v;
  if (region == 1) {  // concatenated + padded (chunks never cross rows: 2048%4==0)
    long r = i >> 11, c = i & 2047;
    if (r < 1536)      v = *(const float4*)(wqa + r * 2048 + c);
    else if (r < 2112) v = *(const float4*)(wkva + (r - 1536) * 2048 + c);
    else               v = (float4){0.f, 0.f, 0.f, 0.f};
  } else {
    v = *(const float4*)(s + i);
  }
  d[i + 0] = f2bf(v.x); d[i + 1] = f2bf(v.y);
  d[i + 2] = f2bf(v.z); d[i + 3] = f2bf(v.w);
}

// ---------------------------------------------------------------------------
// 8-phase GEMM tiles (m201 template, plain HIP). C = A[M,K] * W[N,K]^T.
// Two tile shapes sharing the skeleton:
//   gemm256_tile   : 256x256, acc[8][4], 16 MFMA/phase, LDS 128KB (dual only,
//                    keeps the fused-rope 64-col wave windows)
//   gemm128n_tile  : 256x128, acc[8][2],  8 MFMA/phase, LDS  96KB — used where
//                    the 256x256 grid under-fills the chip (gemm1: 272 blocks,
//                    out: 256 blocks = perfect 1/CU fill vs 144/128 before)
// ---------------------------------------------------------------------------
#define GPHASE(LAc, LBc, QQ, STAGE_STMT, WAIT_STMT)                              \
  {                                                                              \
    short8 a00 = *(const short8*)&(LAc)[agbase + (2*(QQ)) * 1024 + g0];          \
    short8 a01 = *(const short8*)&(LAc)[agbase + (2*(QQ)) * 1024 + g1];          \
    short8 a10 = *(const short8*)&(LAc)[agbase + (2*(QQ)+1) * 1024 + g0];        \
    short8 a11 = *(const short8*)&(LAc)[agbase + (2*(QQ)+1) * 1024 + g1];        \
    if ((QQ) == 0) {                                                             \
      _Pragma("unroll")                                                          \
      for (int fj = 0; fj < 4; ++fj) {                                           \
        bfrg[fj][0] = *(const short8*)&(LBc)[bgbase + fj * 1024 + g0];           \
        bfrg[fj][1] = *(const short8*)&(LBc)[bgbase + fj * 1024 + g1];           \
      }                                                                          \
    }                                                                            \
    STAGE_STMT;                                                                  \
    WAIT_STMT;                                                                   \
    SCHED0();                                                                    \
    SBAR();                                                                      \
    asm volatile("s_waitcnt lgkmcnt(0)" ::: "memory");                           \
    SCHED0();                                                                    \
    __builtin_amdgcn_s_setprio(1);                                               \
    _Pragma("unroll")                                                            \
    for (int fj = 0; fj < 4; ++fj) {                                             \
      acc[2*(QQ)][fj]   = __builtin_amdgcn_mfma_f32_16x16x32_bf16(a00, bfrg[fj][0], acc[2*(QQ)][fj],   0, 0, 0); \
      acc[2*(QQ)][fj]   = __builtin_amdgcn_mfma_f32_16x16x32_bf16(a01, bfrg[fj][1], acc[2*(QQ)][fj],   0, 0, 0); \
      acc[2*(QQ)+1][fj] = __builtin_amdgcn_mfma_f32_16x16x32_bf16(a10, bfrg[fj][0], acc[2*(QQ)+1][fj], 0, 0, 0); \
      acc[2*(QQ)+1][fj] = __builtin_amdgcn_mfma_f32_16x16x32_bf16(a11, bfrg[fj][1], acc[2*(QQ)+1][fj], 0, 0, 0); \
    }                                                                            \
    __builtin_amdgcn_s_setprio(0);                                               \
    SCHED0();                                                                    \
    SBAR();                                                                      \
  }

template <int OUT_F32, int ROPE>
__device__ __forceinline__ void gemm256_tile(
    const u16* __restrict__ A, int lda, const u16* __restrict__ W, int ldw,
    void* __restrict__ Cv, int ldc, int K, int bm, int bn,
    u16* __restrict__ LA, u16* __restrict__ LB,
    const float* __restrict__ cosb, const float* __restrict__ sinb, int smask) {
  int tid = threadIdx.x;
  int lane = tid & 63, w = tid >> 6;
  int wr = w >> 2, wc = w & 3;            // wave grid: 2 (M) x 4 (N)
  int fr = lane & 15, fq = lane >> 4;     // fragment row / k-quad

  int srow = lane >> 3;                   // 0..7
  int sgl  = (lane & 7) ^ srow;           // pre-swizzled source granule

  int agbase = (wr * 128 + fr) * 64;
  int bgbase = (wc * 64 + fr) * 64;
  int g0 = ((0 * 4 + fq) ^ (fr & 7)) * 8;
  int g1 = ((1 * 4 + fq) ^ (fr & 7)) * 8;

  floatx4 acc[8][4];
#pragma unroll
  for (int i = 0; i < 8; i++)
#pragma unroll
    for (int j = 0; j < 4; j++) acc[i][j] = (floatx4){0.f, 0.f, 0.f, 0.f};

  auto stA = [&](int buf, int kt, int half) {
#pragma unroll
    for (int j = 0; j < 2; ++j) {
      int rbase = half * 128 + (w * 2 + j) * 8;
      gld_lds16(A + (size_t)(bm + rbase + srow) * lda + kt * 64 + sgl * 8,
                (void*)&LA[buf * 16384 + rbase * 64]);
    }
  };
  auto stB = [&](int buf, int kt, int half) {
#pragma unroll
    for (int j = 0; j < 2; ++j) {
      int rbase = half * 128 + (w * 2 + j) * 8;
      gld_lds16(W + (size_t)(bn + rbase + srow) * ldw + kt * 64 + sgl * 8,
                (void*)&LB[buf * 16384 + rbase * 64]);
    }
  };

  const u16* LA0 = LA;           const u16* LB0 = LB;
  const u16* LA1 = LA + 16384;   const u16* LB1 = LB + 16384;

  stB(0, 0, 0); stB(0, 0, 1);
  stA(0, 0, 0); stA(0, 0, 1);
  stB(1, 1, 0); stB(1, 1, 1);
  asm volatile("s_waitcnt vmcnt(4)" ::: "memory");
  SCHED0();
  SBAR();

  int NI = K >> 7;   // 2 K-tiles (BK=64) per iteration
  for (int i = 0; i < NI; ++i) {
    bool notlast = (i + 1 < NI);
    int t0 = 2 * i;
    {
      short8 bfrg[4][2];
      GPHASE(LA0, LB0, 0, stA(1, t0 + 1, 0), );
      GPHASE(LA0, LB0, 1, stA(1, t0 + 1, 1), );
      GPHASE(LA0, LB0, 2, if (notlast) stB(0, t0 + 2, 0), );
      GPHASE(LA0, LB0, 3, if (notlast) stB(0, t0 + 2, 1),
             if (notlast) { asm volatile("s_waitcnt vmcnt(4)" ::: "memory"); }
             else         { asm volatile("s_waitcnt vmcnt(0)" ::: "memory"); });
    }
    {
      short8 bfrg[4][2];
      GPHASE(LA1, LB1, 0, if (notlast) stA(0, t0 + 2, 0), );
      GPHASE(LA1, LB1, 1, if (notlast) stA(0, t0 + 2, 1), );
      GPHASE(LA1, LB1, 2, if (notlast) stB(1, t0 + 3, 0), );
      GPHASE(LA1, LB1, 3, if (notlast) stB(1, t0 + 3, 1),
             if (notlast) { asm volatile("s_waitcnt vmcnt(4)" ::: "memory"); });
    }
  }

  int cr = (lane >> 4) * 4, cc = lane & 15;

  // ---- fused q-RoPE on the accumulator (rope window: colwin % 3 == 2) ----
  if (ROPE) {
    int cw = (bn + wc * 64) >> 6;
    if (cw % 3 == 2) {
#pragma unroll
      for (int fi = 0; fi < 8; ++fi)
#pragma unroll
        for (int r = 0; r < 4; ++r) {
          int row = bm + wr * 128 + fi * 16 + cr + r;
          int pos = row & smask;               // token position (S power of 2)
          const float* cb = cosb + pos * 64;
          const float* sb = sinb + pos * 64;
#pragma unroll
          for (int fj = 0; fj < 2; ++fj) {     // pairs (fj, fj+2) = (i, i+32)
            int i1 = fj * 16 + cc;
            float x1 = acc[fi][fj][r], x2 = acc[fi][fj + 2][r];
            acc[fi][fj][r]     = x1 * cb[i1] - x2 * sb[i1];
            acc[fi][fj + 2][r] = x2 * cb[i1 + 32] + x1 * sb[i1 + 32];
          }
        }
    }
  }

#pragma unroll
  for (int fi = 0; fi < 8; ++fi)
#pragma unroll
    for (int fj = 0; fj < 4; ++fj) {
      int col = bn + wc * 64 + fj * 16 + cc;
#pragma unroll
      for (int r = 0; r < 4; ++r) {
        size_t row = (size_t)(bm + wr * 128 + fi * 16 + cr + r);
        if (OUT_F32) ((float*)Cv)[row * ldc + col] = acc[fi][fj][r];
        else         ((u16*)Cv)[row * ldc + col] = f2bf(acc[fi][fj][r]);
      }
    }
}

// Two GEMMs sharing one dispatch: blockIdx.x < nt1 -> GEMM1 (qf, fused rope),
// else GEMM2 (kvb).  256x256 tiles (rope pair locality needs 64-col windows).
__global__ __launch_bounds__(512, 2) void gemm256_dual(
    const u16* __restrict__ A1, int lda1, const u16* __restrict__ W1, int ldw1,
    u16* __restrict__ C1, int ldc1, int K1, int nt1,
    const u16* __restrict__ A2, int lda2, const u16* __restrict__ W2, int ldw2,
    u16* __restrict__ C2, int ldc2, int K2,
    const float* __restrict__ cosb, const float* __restrict__ sinb, int smask) {
  __shared__ __align__(16) u16 LAs[2][256 * 64];
  __shared__ __align__(16) u16 LBs[2][256 * 64];
  int bx = blockIdx.x;
  if (bx < nt1)
    gemm256_tile<0, 1>(A1, lda1, W1, ldw1, C1, ldc1, K1,
                       blockIdx.y * 256, bx * 256, &LAs[0][0], &LBs[0][0],
                       cosb, sinb, smask);
  else
    gemm256_tile<0, 0>(A2, lda2, W2, ldw2, C2, ldc2, K2,
                       blockIdx.y * 256, (bx - nt1) * 256, &LAs[0][0], &LBs[0][0],
                       nullptr, nullptr, 0);
}

// ---------------------------------------------------------------------------
// 256x128-tile variant (better grid fill). Same 8-wave / 8-phase skeleton;
// per-wave output 128x32, acc[8][2], 8 MFMA/phase; stB = 1 load/half;
// steady-state vmcnt(2) (ledger: B(2)+A(4) drained, next-B(2) in flight).
// LDS = 64KB A + 32KB B = 96KB -> 1 block/CU.
// ---------------------------------------------------------------------------
#define GPHASE128(LAc, LBc, QQ, STAGE_STMT, WAIT_STMT)                           \
  {                                                                              \
    short8 a00 = *(const short8*)&(LAc)[agbase + (2*(QQ)) * 1024 + g0];          \
    short8 a01 = *(const short8*)&(LAc)[agbase + (2*(QQ)) * 1024 + g1];          \
    short8 a10 = *(const short8*)&(LAc)[agbase + (2*(QQ)+1) * 1024 + g0];        \
    short8 a11 = *(const short8*)&(LAc)[agbase + (2*(QQ)+1) * 1024 + g1];        \
    if ((QQ) == 0) {                                                             \
      _Pragma("unroll")                                                          \
      for (int fj = 0; fj < 2; ++fj) {                                           \
        bfrg[fj][0] = *(const short8*)&(LBc)[bgbase + fj * 1024 + g0];           \
        bfrg[fj][1] = *(const short8*)&(LBc)[bgbase + fj * 1024 + g1];           \
      }                                                                          \
    }                                                                            \
    STAGE_STMT;                                                                  \
    WAIT_STMT;                                                                   \
    SCHED0();                                                                    \
    SBAR();                                                                      \
    asm volatile("s_waitcnt lgkmcnt(0)" ::: "memory");                           \
    SCHED0();                                                                    \
    __builtin_amdgcn_s_setprio(1);                                               \
    _Pragma("unroll")                                                            \
    for (int fj = 0; fj < 2; ++fj) {                                             \
      acc[2*(QQ)][fj]   = __builtin_amdgcn_mfma_f32_16x16x32_bf16(a00, bfrg[fj][0], acc[2*(QQ)][fj],   0, 0, 0); \
      acc[2*(QQ)][fj]   = __builtin_amdgcn_mfma_f32_16x16x32_bf16(a01, bfrg[fj][1], acc[2*(QQ)][fj],   0, 0, 0); \
      acc[2*(QQ)+1][fj] = __builtin_amdgcn_mfma_f32_16x16x32_bf16(a10, bfrg[fj][0], acc[2*(QQ)+1][fj], 0, 0, 0); \
      acc[2*(QQ)+1][fj] = __builtin_amdgcn_mfma_f32_16x16x32_bf16(a11, bfrg[fj][1], acc[2*(QQ)+1][fj], 0, 0, 0); \
    }                                                                            \
    __builtin_amdgcn_s_setprio(0);                                               \
    SCHED0();                                                                    \
    SBAR();                                                                      \
  }

template <int OUT_F32>
__global__ __launch_bounds__(512, 2) void gemm128n_k(
    const u16* __restrict__ A, int lda,
    const u16* __restrict__ W, int ldw,
    void* __restrict__ Cv, int ldc, int K) {
  __shared__ __align__(16) u16 LA[2][256 * 64];   // 64 KB
  __shared__ __align__(16) u16 LB[2][128 * 64];   // 32 KB
  int bm = blockIdx.y * 256, bn = blockIdx.x * 128;
  int tid = threadIdx.x;
  int lane = tid & 63, w = tid >> 6;
  int wr = w >> 2, wc = w & 3;            // wave grid: 2 (M) x 4 (N)
  int fr = lane & 15, fq = lane >> 4;

  int srow = lane >> 3;
  int sgl  = (lane & 7) ^ srow;           // pre-swizzled source granule

  int agbase = (wr * 128 + fr) * 64;
  int bgbase = (wc * 32 + fr) * 64;
  int g0 = ((0 * 4 + fq) ^ (fr & 7)) * 8;
  int g1 = ((1 * 4 + fq) ^ (fr & 7)) * 8;

  floatx4 acc[8][2];
#pragma unroll
  for (int i = 0; i < 8; i++)
#pragma unroll
    for (int j = 0; j < 2; j++) acc[i][j] = (floatx4){0.f, 0.f, 0.f, 0.f};

  auto stA = [&](int buf, int kt, int half) {   // 2 loads (256-row A tile)
#pragma unroll
    for (int j = 0; j < 2; ++j) {
      int rbase = half * 128 + (w * 2 + j) * 8;
      gld_lds16(A + (size_t)(bm + rbase + srow) * lda + kt * 64 + sgl * 8,
                (void*)&LA[buf][rbase * 64]);
    }
  };
  auto stB = [&](int buf, int kt, int half) {   // 1 load (128-row B tile)
    int rbase = half * 64 + w * 8;
    gld_lds16(W + (size_t)(bn + rbase + srow) * ldw + kt * 64 + sgl * 8,
              (void*)&LB[buf][rbase * 64]);
  };

  const u16* LA0 = &LA[0][0];  const u16* LB0 = &LB[0][0];
  const u16* LA1 = &LA[1][0];  const u16* LB1 = &LB[1][0];

  // prologue: 2(B0) + 4(A0) + 2(B1) loads; drain B0+A0, leave B1 in flight
  stB(0, 0, 0); stB(0, 0, 1);
  stA(0, 0, 0); stA(0, 0, 1);
  stB(1, 1, 0); stB(1, 1, 1);
  asm volatile("s_waitcnt vmcnt(2)" ::: "memory");
  SCHED0();
  SBAR();

  int NI = K >> 7;   // 2 K-tiles (BK=64) per iteration
  for (int i = 0; i < NI; ++i) {
    bool notlast = (i + 1 < NI);
    int t0 = 2 * i;
    {  // even half: compute tile t0 from buf0
      short8 bfrg[2][2];
      GPHASE128(LA0, LB0, 0, stA(1, t0 + 1, 0), );
      GPHASE128(LA0, LB0, 1, stA(1, t0 + 1, 1), );
      GPHASE128(LA0, LB0, 2, if (notlast) stB(0, t0 + 2, 0), );
      GPHASE128(LA0, LB0, 3, if (notlast) stB(0, t0 + 2, 1),
             if (notlast) { asm volatile("s_waitcnt vmcnt(2)" ::: "memory"); }
             else         { asm volatile("s_waitcnt vmcnt(0)" ::: "memory"); });
    }
    {  // odd half: compute tile t0+1 from buf1
      short8 bfrg[2][2];
      GPHASE128(LA1, LB1, 0, if (notlast) stA(0, t0 + 2, 0), );
      GPHASE128(LA1, LB1, 1, if (notlast) stA(0, t0 + 2, 1), );
      GPHASE128(LA1, LB1, 2, if (notlast) stB(1, t0 + 3, 0), );
      GPHASE128(LA1, LB1, 3, if (notlast) stB(1, t0 + 3, 1),
             if (notlast) { asm volatile("s_waitcnt vmcnt(2)" ::: "memory"); });
    }
  }

  int cr = (lane >> 4) * 4, cc = lane & 15;
#pragma unroll
  for (int fi = 0; fi < 8; ++fi)
#pragma unroll
    for (int fj = 0; fj < 2; ++fj) {
      int col = bn + wc * 32 + fj * 16 + cc;
#pragma unroll
      for (int r = 0; r < 4; ++r) {
        size_t row = (size_t)(bm + wr * 128 + fi * 16 + cr + r);
        if (OUT_F32) ((float*)Cv)[row * ldc + col] = acc[fi][fj][r];
        else         ((u16*)Cv)[row * ldc + col] = f2bf(acc[fi][fj][r]);
      }
    }
}

// ---------------------------------------------------------------------------
// Fused per-row: rmsnorm(qa cols 0..1535), rmsnorm(kv cols 1536..2047),
// rope(kpe cols 2048..2111). One block per row of qkv [T, 2176].
// ---------------------------------------------------------------------------
__global__ __launch_bounds__(256) void normrope_k(
    u16* __restrict__ qkv, const float* __restrict__ qnw,
    const float* __restrict__ kvnw, const float* __restrict__ cosb,
    const float* __restrict__ sinb, int S) {
  int row = blockIdx.x, tid = threadIdx.x;
  u16* p = qkv + (size_t)row * 2176;
  float s1 = 0.f, s2 = 0.f;
#pragma unroll
  for (int it = 0; it < 6; it++) { float v = bf2f(p[tid + 256 * it]); s1 += v * v; }
#pragma unroll
  for (int it = 0; it < 2; it++) { float v = bf2f(p[1536 + tid + 256 * it]); s2 += v * v; }
  for (int off = 32; off > 0; off >>= 1) {
    s1 += __shfl_down(s1, off);
    s2 += __shfl_down(s2, off);
  }
  __shared__ float red1[4], red2[4];
  if ((tid & 63) == 0) { red1[tid >> 6] = s1; red2[tid >> 6] = s2; }
  __syncthreads();
  float inv1 = rsqrtf((red1[0] + red1[1] + red1[2] + red1[3]) / 1536.f + 1e-6f);
  float inv2 = rsqrtf((red2[0] + red2[1] + red2[2] + red2[3]) / 512.f + 1e-6f);
#pragma unroll
  for (int it = 0; it < 6; it++) {
    int i = tid + 256 * it;
    p[i] = f2bf(bf2f(p[i]) * inv1 * qnw[i]);
  }
#pragma unroll
  for (int it = 0; it < 2; it++) {
    int i = tid + 256 * it;
    p[1536 + i] = f2bf(bf2f(p[1536 + i]) * inv2 * kvnw[i]);
  }
  if (tid < 32) {
    int pos = row % S;
    float c1 = cosb[pos * 64 + tid];
    float c2 = cosb[pos * 64 + tid + 32];
    float sn1 = sinb[pos * 64 + tid];
    float sn2 = sinb[pos * 64 + tid + 32];
    float x1 = bf2f(p[2048 + tid]), x2 = bf2f(p[2048 + tid + 32]);
    p[2048 + tid]      = f2bf(x1 * c1 - x2 * sn1);
    p[2048 + tid + 32] = f2bf(x2 * c2 + x1 * sn2);
  }
}

// ---------------------------------------------------------------------------
// V transpose: kvb V-part [tok][h*256+128+vd] -> vt[((b*16+h)*128+vd)*S + tok]
// ---------------------------------------------------------------------------
__global__ __launch_bounds__(256) void vtrans_k(
    const u16* __restrict__ kvb, u16* __restrict__ vt, int S) {
  int tb = blockIdx.x, h = blockIdx.y, b = blockIdx.z;
  __shared__ __align__(16) u16 Ts[64][136];
  int tid = threadIdx.x;
#pragma unroll
  for (int it = 0; it < 4; it++) {
    int e = tid + 256 * it;
    int tok = e >> 4, c = e & 15;
    short8 v = *(const short8*)(kvb + (size_t)(b * S + tb * 64 + tok) * 4096 + h * 256 + 128 + c * 8);
    *(short8*)&Ts[tok][c * 8] = v;
  }
  __syncthreads();
  int vd = tid >> 1, half = (tid & 1) * 32;
  u16 tmp[32];
#pragma unroll
  for (int j = 0; j < 32; j++) tmp[j] = Ts[half + j][vd];
  u16* dst = vt + ((size_t)((b * 16 + h) * 128) + vd) * S + tb * 64 + half;
#pragma unroll
  for (int c = 0; c < 4; c++)
    *(short8*)(dst + c * 8) = *(short8*)&tmp[c * 8];
}

// ---------------------------------------------------------------------------
// MFMA flash attention. PAIRED q-tiles (uniform work: every block exactly
// NT+1 k-iterations), XCD-grouped dispatch, T5 setprio, T13 defer-rescale,
// __expf fast path. Round-3 schedule (3 barriers/iter) — measured optimum;
// r4/r6/r7/r8 perturbations all regressed.
// ---------------------------------------------------------------------------
#define AT_BK 64
__global__ __launch_bounds__(256) void attn_mfma(
    const u16* __restrict__ qf, const u16* __restrict__ kvb,
    const u16* __restrict__ kpe, int kpe_stride, const u16* __restrict__ vt,
    u16* __restrict__ at, int S) {
  int id = blockIdx.x;
  int pair = id >> 5, hb = id & 31;
  int h = hb & 15, b = hb >> 4;
  int NT = S / AT_BK;
  int tid = threadIdx.x, lane = tid & 63, w = tid >> 6;
  int fr = lane & 15, fq = lane >> 4;   // fragment row / k-quad
  int fs = fr & 7;                      // swizzle key for reads

  __shared__ __align__(16) u16 Ksn[AT_BK * 128];  // [key][16 chunks]
  __shared__ __align__(16) u16 Ksp[AT_BK * 64];   // [key][8 chunks]
  __shared__ __align__(16) u16 Vts[128 * AT_BK];  // [vd][8 chunks]
  __shared__ __align__(16) u16 Ps[64 * AT_BK];    // [qrow][8 chunks]

  const float scale = 0.07216878364870323f;  // 192^-0.5

  for (int p = 0; p < 2; p++) {
    int qt = p ? (NT - 1 - pair) : pair;
    int q0 = qt * 64;

    // Q fragments direct from global: A[m=fr][k=fq*8+j], 6 k-steps of 32
    short8 qfrag[6];
    {
      const u16* qrow = qf + (size_t)(b * S + q0 + w * 16 + fr) * 3072 + h * 192 + fq * 8;
#pragma unroll
      for (int ks = 0; ks < 6; ks++) qfrag[ks] = *(const short8*)(qrow + ks * 32);
    }

    floatx4 acc_o[8];
#pragma unroll
    for (int j = 0; j < 8; j++) acc_o[j] = (floatx4){0.f, 0.f, 0.f, 0.f};
    float m_r[4], l_r[4];   // l_r: per-lane PARTIAL sums (reduced in epilogue)
#pragma unroll
    for (int r = 0; r < 4; r++) { m_r[r] = -3e38f; l_r[r] = 0.f; }

    for (int kt = 0; kt <= qt; kt++) {
      int k0 = kt * AT_BK;
      size_t tokbase = (size_t)(b * S + k0);
      // ---- stage K (nope+pe) and V^T with swizzled per-lane global chunk ----
#pragma unroll
      for (int c = 0; c < 4; c++) {  // Ksn: 4 rows/call, 16 chunks/row
        int row = w * 16 + c * 4 + (lane >> 4);
        int cg = (lane & 15) ^ (row & 7);
        gld_lds16(kvb + (tokbase + row) * 4096 + h * 256 + cg * 8,
                  &Ksn[(w * 16 + c * 4) * 128]);
      }
#pragma unroll
      for (int c = 0; c < 2; c++) {  // Ksp: 8 rows/call, 8 chunks/row
        int row = w * 16 + c * 8 + (lane >> 3);
        int cg = (lane & 7) ^ (row & 7);
        gld_lds16(kpe + (tokbase + row) * kpe_stride + cg * 8,
                  &Ksp[(w * 16 + c * 8) * 64]);
      }
#pragma unroll
      for (int c = 0; c < 4; c++) {  // Vts: 8 vd-rows/call, 8 chunks/row
        int vd = w * 32 + c * 8 + (lane >> 3);
        int cg = (lane & 7) ^ (vd & 7);
        gld_lds16(vt + ((size_t)((b * 16 + h) * 128) + vd) * S + k0 + cg * 8,
                  &Vts[(w * 32 + c * 8) * 64]);
      }
      __syncthreads();

      // ---- S = Q K^T for wave's 16 rows x 64 keys ----
      floatx4 accs[4];
#pragma unroll
      for (int nt = 0; nt < 4; nt++) accs[nt] = (floatx4){0.f, 0.f, 0.f, 0.f};
      __builtin_amdgcn_s_setprio(1);
#pragma unroll
      for (int nt = 0; nt < 4; nt++) {
#pragma unroll
        for (int ks = 0; ks < 4; ks++) {
          short8 bf = *(const short8*)&Ksn[(nt * 16 + fr) * 128 + ((ks * 4 + fq) ^ fs) * 8];
          accs[nt] = __builtin_amdgcn_mfma_f32_16x16x32_bf16(qfrag[ks], bf, accs[nt], 0, 0, 0);
        }
#pragma unroll
        for (int ks = 0; ks < 2; ks++) {
          short8 bf = *(const short8*)&Ksp[(nt * 16 + fr) * 64 + ((ks * 4 + fq) ^ fs) * 8];
          accs[nt] = __builtin_amdgcn_mfma_f32_16x16x32_bf16(qfrag[4 + ks], bf, accs[nt], 0, 0, 0);
        }
      }
      __builtin_amdgcn_s_setprio(0);

      // ---- scale + causal mask (diagonal tile only) ----
      bool diag = (kt == qt);
#pragma unroll
      for (int nt = 0; nt < 4; nt++)
#pragma unroll
        for (int r = 0; r < 4; r++) {
          float s = accs[nt][r] * scale;
          if (diag) {
            int col = nt * 16 + fr;
            int row = fq * 4 + r;
            if (k0 + col > q0 + w * 16 + row) s = -3e38f;
          }
          accs[nt][r] = s;
        }

      // ---- online softmax with defer-rescale (T13, THR=8) ----
      float mx4[4];
      int grow = 0;
#pragma unroll
      for (int r = 0; r < 4; r++) {
        float mx = fmaxf(fmaxf(accs[0][r], accs[1][r]), fmaxf(accs[2][r], accs[3][r]));
        mx = fmaxf(mx, __shfl_xor(mx, 1));
        mx = fmaxf(mx, __shfl_xor(mx, 2));
        mx = fmaxf(mx, __shfl_xor(mx, 4));
        mx = fmaxf(mx, __shfl_xor(mx, 8));
        mx4[r] = mx;
        grow |= (mx > m_r[r] + 8.f) ? 1 : 0;
      }
      bool resc = __any(grow);   // wave-uniform decision
      float alpha[4];
      if (resc) {
#pragma unroll
        for (int r = 0; r < 4; r++) {
          float mnew = fmaxf(m_r[r], mx4[r]);
          alpha[r] = __expf(m_r[r] - mnew);
          m_r[r] = mnew;
          l_r[r] *= alpha[r];
        }
      }
#pragma unroll
      for (int nt = 0; nt < 4; nt++)
#pragma unroll
        for (int r = 0; r < 4; r++) {
          float pv = __expf(accs[nt][r] - m_r[r]);   // bounded by e^8 when deferred
          l_r[r] += pv;
          int row_p = w * 16 + fq * 4 + r;
          int col = nt * 16 + fr;
          Ps[row_p * 64 + (((col >> 3) ^ (row_p & 7)) * 8) + (col & 7)] = f2bf(pv);
        }
      __syncthreads();   // Ps visible to PV reads (r8: removing this cost +8us)

      // ---- O = O*alpha + P V ----
      if (resc) {
#pragma unroll
        for (int j = 0; j < 8; j++)
#pragma unroll
          for (int r = 0; r < 4; r++) acc_o[j][r] *= alpha[r];
      }
      short8 pf0 = *(const short8*)&Ps[(w * 16 + fr) * 64 + (fq ^ fs) * 8];
      short8 pf1 = *(const short8*)&Ps[(w * 16 + fr) * 64 + ((4 + fq) ^ fs) * 8];
      __builtin_amdgcn_s_setprio(1);
#pragma unroll
      for (int j = 0; j < 8; j++) {
        short8 v0 = *(const short8*)&Vts[(j * 16 + fr) * 64 + (fq ^ fs) * 8];
        short8 v1 = *(const short8*)&Vts[(j * 16 + fr) * 64 + ((4 + fq) ^ fs) * 8];
        acc_o[j] = __builtin_amdgcn_mfma_f32_16x16x32_bf16(pf0, v0, acc_o[j], 0, 0, 0);
        acc_o[j] = __builtin_amdgcn_mfma_f32_16x16x32_bf16(pf1, v1, acc_o[j], 0, 0, 0);
      }
      __builtin_amdgcn_s_setprio(0);
      __syncthreads();   // before next tile's staging overwrites LDS
    }

    // ---- epilogue: reduce per-lane l partials across the row's 16 lanes ----
    float inv_l[4];
#pragma unroll
    for (int r = 0; r < 4; r++) {
      float sm = l_r[r];
      sm += __shfl_xor(sm, 1);
      sm += __shfl_xor(sm, 2);
      sm += __shfl_xor(sm, 4);
      sm += __shfl_xor(sm, 8);
      inv_l[r] = 1.f / sm;
    }
#pragma unroll
    for (int j = 0; j < 8; j++)
#pragma unroll
      for (int r = 0; r < 4; r++) {
        size_t row = (size_t)(b * S + q0 + w * 16 + fq * 4 + r);
        at[row * 2048 + h * 128 + j * 16 + fr] = f2bf(acc_o[j][r] * inv_l[r]);
      }
  }
}

// ---------------------------------------------------------------------------
extern "C" void kernel_launch(void* const* d_in, const int* in_sizes, int n_in,
                              void* d_out, int out_size, void* d_ws, size_t ws_size,
                              hipStream_t stream) {
  (void)in_sizes; (void)n_in; (void)out_size; (void)ws_size;
  const float* x     = (const float*)d_in[0];
  const float* cosb  = (const float*)d_in[1];
  const float* sinb  = (const float*)d_in[2];
  const float* wq_a  = (const float*)d_in[3];
  const float* qnw   = (const float*)d_in[4];
  const float* wq_b  = (const float*)d_in[5];
  const float* wkv_a = (const float*)d_in[6];
  const float* kvnw  = (const float*)d_in[7];
  const float* wkv_b = (const float*)d_in[8];
  const float* wo    = (const float*)d_in[9];
  float* out = (float*)d_out;
  const int B = 2, S = 2048, T = B * S;

  char* wsb = (char*)d_ws;
  size_t off = 0;
  u16* xb   = (u16*)(wsb + off); off += (size_t)T * 2048 * 2;
  u16* wcat = (u16*)(wsb + off); off += (size_t)2176 * 2048 * 2;  // wq_a|wkv_a|pad
  u16* wqbb = (u16*)(wsb + off); off += (size_t)3072 * 1536 * 2;
  u16* wkbb = (u16*)(wsb + off); off += (size_t)4096 * 512 * 2;
  u16* wob  = (u16*)(wsb + off); off += (size_t)2048 * 2048 * 2;
  u16* qkv  = (u16*)(wsb + off); off += (size_t)T * 2176 * 2;     // qa|kv|kpe
  u16* qf   = (u16*)(wsb + off); off += (size_t)T * 3072 * 2;
  u16* kvb  = (u16*)(wsb + off); off += (size_t)T * 4096 * 2;
  u16* at   = (u16*)(wsb + off); off += (size_t)T * 2048 * 2;
  u16* vt   = xb;   // reuse: xb dead after GEMM 1; same size (T*2048)

  // 0) all repacks in one dispatch
  repack_all_k<<<dim3(8192, 5), 256, 0, stream>>>(
      x, wq_a, wkv_a, wq_b, wkv_b, wo, xb, wcat, wqbb, wkbb, wob);

  // 1) qkv = xb @ [wq_a;wkv_a]^T  [T,2176]  (256x128 tiles: 17x16=272 blocks)
  gemm128n_k<0><<<dim3(2176 / 128, T / 256), 512, 0, stream>>>(xb, 2048, wcat, 2048, qkv, 2176, 2048);
  // 2) fused: rmsnorm(qa), rmsnorm(kv), rope(kpe)
  normrope_k<<<T, 256, 0, stream>>>(qkv, qnw, kvnw, cosb, sinb, S);
  // 3) merged: qf = qa @ wq_b^T [T,3072] (+ fused q-RoPE on accumulator)
  //    AND kvb = kv @ wkv_b^T [T,4096]  (256x256 tiles, rope pair locality)
  gemm256_dual<<<dim3(3072 / 256 + 4096 / 256, T / 256), 512, 0, stream>>>(
      qkv, 2176, wqbb, 1536, qf, 3072, 1536, 3072 / 256,
      qkv + 1536, 2176, wkbb, 512, kvb, 4096, 512,
      cosb, sinb, S - 1);
  // 4) V transpose (vt overlays dead xb)
  vtrans_k<<<dim3(S / 64, 16, B), 256, 0, stream>>>(kvb, vt, S);
  // 5) MFMA flash attention (paired q-tiles, XCD-grouped, r3 schedule)
  attn_mfma<<<dim3((S / 128) * 32), 256, 0, stream>>>(qf, kvb, qkv + 2048, 2176, vt, at, S);
  // 6) out = at @ wo^T [T,2048] fp32 (256x128 tiles: 16x16=256 blocks, full fill)
  gemm128n_k<1><<<dim3(2048 / 128, T / 256), 512, 0, stream>>>(at, 2048, wob, 2048, out, 2048, 2048);
}

// Round 11
// 460.429 us; speedup vs baseline: 1.0104x; 1.0104x over previous
//
#include <hip/hip_runtime.h>

typedef unsigned short u16;
typedef __attribute__((ext_vector_type(8))) short short8;   // 8 bf16 = 4 VGPRs
typedef __attribute__((ext_vector_type(4))) float floatx4;

__device__ __forceinline__ float bf2f(u16 u) {
  union { unsigned int i; float f; } v; v.i = ((unsigned int)u) << 16; return v.f;
}
__device__ __forceinline__ u16 f2bf(float f) {
  union { float f; unsigned int i; } v; v.f = f;
  unsigned int u = v.i;
  u += 0x7fffu + ((u >> 16) & 1u);   // RNE
  return (u16)(u >> 16);
}

__device__ __forceinline__ void gld_lds16(const void* g, void* l) {
  __builtin_amdgcn_global_load_lds(
      (const __attribute__((address_space(1))) unsigned int*)g,
      (__attribute__((address_space(3))) unsigned int*)l, 16, 0, 0);
}

#define SBAR()   __builtin_amdgcn_s_barrier()
#define SCHED0() __builtin_amdgcn_sched_barrier(0)

// ---------------------------------------------------------------------------
// One-shot repack: blockIdx.y selects region.
//  0: x      [4096,2048] -> xb
//  1: wcat   rows 0..1535 wq_a, 1536..2111 wkv_a, 2112..2303 zero  (cols 2048)
//  2: wq_b   [3072,1536] -> wqbb
//  3: wkv_b  [4096,512]  -> wkbb
//  4: wo     [2048,2048] -> wob
// ---------------------------------------------------------------------------
__global__ __launch_bounds__(256) void repack_all_k(
    const float* __restrict__ x, const float* __restrict__ wqa,
    const float* __restrict__ wkva, const float* __restrict__ wqb,
    const float* __restrict__ wkvb, const float* __restrict__ wo,
    u16* __restrict__ xb, u16* __restrict__ wcat, u16* __restrict__ wqbb,
    u16* __restrict__ wkbb, u16* __restrict__ wob) {
  long i = ((long)blockIdx.x * 256 + threadIdx.x) * 4;
  int region = blockIdx.y;
  const float* s = nullptr; u16* d = nullptr; long n = 0;
  switch (region) {
    case 0: s = x;    d = xb;   n = 4096L * 2048; break;
    case 1: s = nullptr; d = wcat; n = 2304L * 2048; break;
    case 2: s = wqb;  d = wqbb; n = 3072L * 1536; break;
    case 3: s = wkvb; d = wkbb; n = 4096L * 512;  break;
    case 4: s = wo;   d = wob;  n = 2048L * 2048; break;
  }
  if (i >= n) return;
  float4 v;
  if (region == 1) {  // concatenated + padded (chunks never cross rows: 2048%4==0)
    long r = i >> 11, c = i & 2047;
    if (r < 1536)      v = *(const float4*)(wqa + r * 2048 + c);
    else if (r < 2112) v = *(const float4*)(wkva + (r - 1536) * 2048 + c);
    else               v = (float4){0.f, 0.f, 0.f, 0.f};
  } else {
    v = *(const float4*)(s + i);
  }
  d[i + 0] = f2bf(v.x); d[i + 1] = f2bf(v.y);
  d[i + 2] = f2bf(v.z); d[i + 3] = f2bf(v.w);
}

// ---------------------------------------------------------------------------
// 256x256 8-phase GEMM (m201 template, plain HIP). C = A[M,K] * W[N,K]^T.
// 512 threads (8 waves, 2Mx4N), BK=64, 2 K-tiles/iter, LDS 128 KiB dbuf,
// XOR-granule swizzle, counted vmcnt(4) at phases 4/8, setprio on MFMA.
// ROPE=1: fused q-RoPE on 64-col windows where ((bn+wc*64)/64)%3==2 —
// pair (i,i+32) = acc[fi][fj]/acc[fi][fj+2], same lane, zero cross-lane.
// Requires: M%256==0, N%256==0, K%128==0.
// ---------------------------------------------------------------------------
#define GPHASE(LAc, LBc, QQ, STAGE_STMT, WAIT_STMT)                              \
  {                                                                              \
    short8 a00 = *(const short8*)&(LAc)[agbase + (2*(QQ)) * 1024 + g0];          \
    short8 a01 = *(const short8*)&(LAc)[agbase + (2*(QQ)) * 1024 + g1];          \
    short8 a10 = *(const short8*)&(LAc)[agbase + (2*(QQ)+1) * 1024 + g0];        \
    short8 a11 = *(const short8*)&(LAc)[agbase + (2*(QQ)+1) * 1024 + g1];        \
    if ((QQ) == 0) {                                                             \
      _Pragma("unroll")                                                          \
      for (int fj = 0; fj < 4; ++fj) {                                           \
        bfrg[fj][0] = *(const short8*)&(LBc)[bgbase + fj * 1024 + g0];           \
        bfrg[fj][1] = *(const short8*)&(LBc)[bgbase + fj * 1024 + g1];           \
      }                                                                          \
    }                                                                            \
    STAGE_STMT;                                                                  \
    WAIT_STMT;                                                                   \
    SCHED0();                                                                    \
    SBAR();                                                                      \
    asm volatile("s_waitcnt lgkmcnt(0)" ::: "memory");                           \
    SCHED0();                                                                    \
    __builtin_amdgcn_s_setprio(1);                                               \
    _Pragma("unroll")                                                            \
    for (int fj = 0; fj < 4; ++fj) {                                             \
      acc[2*(QQ)][fj]   = __builtin_amdgcn_mfma_f32_16x16x32_bf16(a00, bfrg[fj][0], acc[2*(QQ)][fj],   0, 0, 0); \
      acc[2*(QQ)][fj]   = __builtin_amdgcn_mfma_f32_16x16x32_bf16(a01, bfrg[fj][1], acc[2*(QQ)][fj],   0, 0, 0); \
      acc[2*(QQ)+1][fj] = __builtin_amdgcn_mfma_f32_16x16x32_bf16(a10, bfrg[fj][0], acc[2*(QQ)+1][fj], 0, 0, 0); \
      acc[2*(QQ)+1][fj] = __builtin_amdgcn_mfma_f32_16x16x32_bf16(a11, bfrg[fj][1], acc[2*(QQ)+1][fj], 0, 0, 0); \
    }                                                                            \
    __builtin_amdgcn_s_setprio(0);                                               \
    SCHED0();                                                                    \
    SBAR();                                                                      \
  }

template <int OUT_F32, int ROPE>
__device__ __forceinline__ void gemm256_tile(
    const u16* __restrict__ A, int lda, const u16* __restrict__ W, int ldw,
    void* __restrict__ Cv, int ldc, int K, int bm, int bn,
    u16* __restrict__ LA, u16* __restrict__ LB,
    const float* __restrict__ cosb, const float* __restrict__ sinb, int smask) {
  int tid = threadIdx.x;
  int lane = tid & 63, w = tid >> 6;
  int wr = w >> 2, wc = w & 3;            // wave grid: 2 (M) x 4 (N)
  int fr = lane & 15, fq = lane >> 4;     // fragment row / k-quad

  int srow = lane >> 3;                   // 0..7
  int sgl  = (lane & 7) ^ srow;           // pre-swizzled source granule

  int agbase = (wr * 128 + fr) * 64;
  int bgbase = (wc * 64 + fr) * 64;
  int g0 = ((0 * 4 + fq) ^ (fr & 7)) * 8;
  int g1 = ((1 * 4 + fq) ^ (fr & 7)) * 8;

  floatx4 acc[8][4];
#pragma unroll
  for (int i = 0; i < 8; i++)
#pragma unroll
    for (int j = 0; j < 4; j++) acc[i][j] = (floatx4){0.f, 0.f, 0.f, 0.f};

  auto stA = [&](int buf, int kt, int half) {
#pragma unroll
    for (int j = 0; j < 2; ++j) {
      int rbase = half * 128 + (w * 2 + j) * 8;
      gld_lds16(A + (size_t)(bm + rbase + srow) * lda + kt * 64 + sgl * 8,
                (void*)&LA[buf * 16384 + rbase * 64]);
    }
  };
  auto stB = [&](int buf, int kt, int half) {
#pragma unroll
    for (int j = 0; j < 2; ++j) {
      int rbase = half * 128 + (w * 2 + j) * 8;
      gld_lds16(W + (size_t)(bn + rbase + srow) * ldw + kt * 64 + sgl * 8,
                (void*)&LB[buf * 16384 + rbase * 64]);
    }
  };

  const u16* LA0 = LA;           const u16* LB0 = LB;
  const u16* LA1 = LA + 16384;   const u16* LB1 = LB + 16384;

  stB(0, 0, 0); stB(0, 0, 1);
  stA(0, 0, 0); stA(0, 0, 1);
  stB(1, 1, 0); stB(1, 1, 1);
  asm volatile("s_waitcnt vmcnt(4)" ::: "memory");
  SCHED0();
  SBAR();

  int NI = K >> 7;   // 2 K-tiles (BK=64) per iteration
  for (int i = 0; i < NI; ++i) {
    bool notlast = (i + 1 < NI);
    int t0 = 2 * i;
    {
      short8 bfrg[4][2];
      GPHASE(LA0, LB0, 0, stA(1, t0 + 1, 0), );
      GPHASE(LA0, LB0, 1, stA(1, t0 + 1, 1), );
      GPHASE(LA0, LB0, 2, if (notlast) stB(0, t0 + 2, 0), );
      GPHASE(LA0, LB0, 3, if (notlast) stB(0, t0 + 2, 1),
             if (notlast) { asm volatile("s_waitcnt vmcnt(4)" ::: "memory"); }
             else         { asm volatile("s_waitcnt vmcnt(0)" ::: "memory"); });
    }
    {
      short8 bfrg[4][2];
      GPHASE(LA1, LB1, 0, if (notlast) stA(0, t0 + 2, 0), );
      GPHASE(LA1, LB1, 1, if (notlast) stA(0, t0 + 2, 1), );
      GPHASE(LA1, LB1, 2, if (notlast) stB(1, t0 + 3, 0), );
      GPHASE(LA1, LB1, 3, if (notlast) stB(1, t0 + 3, 1),
             if (notlast) { asm volatile("s_waitcnt vmcnt(4)" ::: "memory"); });
    }
  }

  int cr = (lane >> 4) * 4, cc = lane & 15;

  // ---- fused q-RoPE on the accumulator (rope window: colwin % 3 == 2) ----
  if (ROPE) {
    int cw = (bn + wc * 64) >> 6;
    if (cw % 3 == 2) {
#pragma unroll
      for (int fi = 0; fi < 8; ++fi)
#pragma unroll
        for (int r = 0; r < 4; ++r) {
          int row = bm + wr * 128 + fi * 16 + cr + r;
          int pos = row & smask;               // token position (S power of 2)
          const float* cb = cosb + pos * 64;
          const float* sb = sinb + pos * 64;
#pragma unroll
          for (int fj = 0; fj < 2; ++fj) {     // pairs (fj, fj+2) = (i, i+32)
            int i1 = fj * 16 + cc;
            float x1 = acc[fi][fj][r], x2 = acc[fi][fj + 2][r];
            acc[fi][fj][r]     = x1 * cb[i1] - x2 * sb[i1];
            acc[fi][fj + 2][r] = x2 * cb[i1 + 32] + x1 * sb[i1 + 32];
          }
        }
    }
  }

#pragma unroll
  for (int fi = 0; fi < 8; ++fi)
#pragma unroll
    for (int fj = 0; fj < 4; ++fj) {
      int col = bn + wc * 64 + fj * 16 + cc;
#pragma unroll
      for (int r = 0; r < 4; ++r) {
        size_t row = (size_t)(bm + wr * 128 + fi * 16 + cr + r);
        if (OUT_F32) ((float*)Cv)[row * ldc + col] = acc[fi][fj][r];
        else         ((u16*)Cv)[row * ldc + col] = f2bf(acc[fi][fj][r]);
      }
    }
}

template <int OUT_F32>
__global__ __launch_bounds__(512, 2) void gemm256_k(
    const u16* __restrict__ A, int lda,
    const u16* __restrict__ W, int ldw,
    void* __restrict__ Cv, int ldc, int K) {
  __shared__ __align__(16) u16 LAs[2][256 * 64];
  __shared__ __align__(16) u16 LBs[2][256 * 64];
  gemm256_tile<OUT_F32, 0>(A, lda, W, ldw, Cv, ldc, K,
                           blockIdx.y * 256, blockIdx.x * 256,
                           &LAs[0][0], &LBs[0][0], nullptr, nullptr, 0);
}

// Two GEMMs sharing one dispatch: blockIdx.x < nt1 -> GEMM1 (qf, fused rope),
// else GEMM2 (kvb).
__global__ __launch_bounds__(512, 2) void gemm256_dual(
    const u16* __restrict__ A1, int lda1, const u16* __restrict__ W1, int ldw1,
    u16* __restrict__ C1, int ldc1, int K1, int nt1,
    const u16* __restrict__ A2, int lda2, const u16* __restrict__ W2, int ldw2,
    u16* __restrict__ C2, int ldc2, int K2,
    const float* __restrict__ cosb, const float* __restrict__ sinb, int smask) {
  __shared__ __align__(16) u16 LAs[2][256 * 64];
  __shared__ __align__(16) u16 LBs[2][256 * 64];
  int bx = blockIdx.x;
  if (bx < nt1)
    gemm256_tile<0, 1>(A1, lda1, W1, ldw1, C1, ldc1, K1,
                       blockIdx.y * 256, bx * 256, &LAs[0][0], &LBs[0][0],
                       cosb, sinb, smask);
  else
    gemm256_tile<0, 0>(A2, lda2, W2, ldw2, C2, ldc2, K2,
                       blockIdx.y * 256, (bx - nt1) * 256, &LAs[0][0], &LBs[0][0],
                       nullptr, nullptr, 0);
}

// ---------------------------------------------------------------------------
// Fused per-row: rmsnorm(qa cols 0..1535), rmsnorm(kv cols 1536..2047),
// rope(kpe cols 2048..2111). One block per row of qkv [T, 2304].
// ---------------------------------------------------------------------------
__global__ __launch_bounds__(256) void normrope_k(
    u16* __restrict__ qkv, const float* __restrict__ qnw,
    const float* __restrict__ kvnw, const float* __restrict__ cosb,
    const float* __restrict__ sinb, int S) {
  int row = blockIdx.x, tid = threadIdx.x;
  u16* p = qkv + (size_t)row * 2304;
  float s1 = 0.f, s2 = 0.f;
#pragma unroll
  for (int it = 0; it < 6; it++) { float v = bf2f(p[tid + 256 * it]); s1 += v * v; }
#pragma unroll
  for (int it = 0; it < 2; it++) { float v = bf2f(p[1536 + tid + 256 * it]); s2 += v * v; }
  for (int off = 32; off > 0; off >>= 1) {
    s1 += __shfl_down(s1, off);
    s2 += __shfl_down(s2, off);
  }
  __shared__ float red1[4], red2[4];
  if ((tid & 63) == 0) { red1[tid >> 6] = s1; red2[tid >> 6] = s2; }
  __syncthreads();
  float inv1 = rsqrtf((red1[0] + red1[1] + red1[2] + red1[3]) / 1536.f + 1e-6f);
  float inv2 = rsqrtf((red2[0] + red2[1] + red2[2] + red2[3]) / 512.f + 1e-6f);
#pragma unroll
  for (int it = 0; it < 6; it++) {
    int i = tid + 256 * it;
    p[i] = f2bf(bf2f(p[i]) * inv1 * qnw[i]);
  }
#pragma unroll
  for (int it = 0; it < 2; it++) {
    int i = tid + 256 * it;
    p[1536 + i] = f2bf(bf2f(p[1536 + i]) * inv2 * kvnw[i]);
  }
  if (tid < 32) {
    int pos = row % S;
    float c1 = cosb[pos * 64 + tid];
    float c2 = cosb[pos * 64 + tid + 32];
    float sn1 = sinb[pos * 64 + tid];
    float sn2 = sinb[pos * 64 + tid + 32];
    float x1 = bf2f(p[2048 + tid]), x2 = bf2f(p[2048 + tid + 32]);
    p[2048 + tid]      = f2bf(x1 * c1 - x2 * sn1);
    p[2048 + tid + 32] = f2bf(x2 * c2 + x1 * sn2);
  }
}

// ---------------------------------------------------------------------------
// V transpose: kvb V-part [tok][h*256+128+vd] -> vt[((b*16+h)*128+vd)*S + tok]
// ---------------------------------------------------------------------------
__global__ __launch_bounds__(256) void vtrans_k(
    const u16* __restrict__ kvb, u16* __restrict__ vt, int S) {
  int tb = blockIdx.x, h = blockIdx.y, b = blockIdx.z;
  __shared__ __align__(16) u16 Ts[64][136];
  int tid = threadIdx.x;
#pragma unroll
  for (int it = 0; it < 4; it++) {
    int e = tid + 256 * it;
    int tok = e >> 4, c = e & 15;
    short8 v = *(const short8*)(kvb + (size_t)(b * S + tb * 64 + tok) * 4096 + h * 256 + 128 + c * 8);
    *(short8*)&Ts[tok][c * 8] = v;
  }
  __syncthreads();
  int vd = tid >> 1, half = (tid & 1) * 32;
  u16 tmp[32];
#pragma unroll
  for (int j = 0; j < 32; j++) tmp[j] = Ts[half + j][vd];
  u16* dst = vt + ((size_t)((b * 16 + h) * 128) + vd) * S + tb * 64 + half;
#pragma unroll
  for (int c = 0; c < 4; c++)
    *(short8*)(dst + c * 8) = *(short8*)&tmp[c * 8];
}

// ---------------------------------------------------------------------------
// MFMA flash attention. PAIRED q-tiles (uniform work: every block exactly
// NT+1 k-iterations), XCD-grouped dispatch, T5 setprio, T13 defer-rescale,
// __expf fast path. Round-3 schedule (3 barriers/iter) — measured optimum;
// r4/r6/r7/r8 perturbations all regressed.
// ---------------------------------------------------------------------------
#define AT_BK 64
__global__ __launch_bounds__(256) void attn_mfma(
    const u16* __restrict__ qf, const u16* __restrict__ kvb,
    const u16* __restrict__ kpe, int kpe_stride, const u16* __restrict__ vt,
    u16* __restrict__ at, int S) {
  int id = blockIdx.x;
  int pair = id >> 5, hb = id & 31;
  int h = hb & 15, b = hb >> 4;
  int NT = S / AT_BK;
  int tid = threadIdx.x, lane = tid & 63, w = tid >> 6;
  int fr = lane & 15, fq = lane >> 4;   // fragment row / k-quad
  int fs = fr & 7;                      // swizzle key for reads

  __shared__ __align__(16) u16 Ksn[AT_BK * 128];  // [key][16 chunks]
  __shared__ __align__(16) u16 Ksp[AT_BK * 64];   // [key][8 chunks]
  __shared__ __align__(16) u16 Vts[128 * AT_BK];  // [vd][8 chunks]
  __shared__ __align__(16) u16 Ps[64 * AT_BK];    // [qrow][8 chunks]

  const float scale = 0.07216878364870323f;  // 192^-0.5

  for (int p = 0; p < 2; p++) {
    int qt = p ? (NT - 1 - pair) : pair;
    int q0 = qt * 64;

    // Q fragments direct from global: A[m=fr][k=fq*8+j], 6 k-steps of 32
    short8 qfrag[6];
    {
      const u16* qrow = qf + (size_t)(b * S + q0 + w * 16 + fr) * 3072 + h * 192 + fq * 8;
#pragma unroll
      for (int ks = 0; ks < 6; ks++) qfrag[ks] = *(const short8*)(qrow + ks * 32);
    }

    floatx4 acc_o[8];
#pragma unroll
    for (int j = 0; j < 8; j++) acc_o[j] = (floatx4){0.f, 0.f, 0.f, 0.f};
    float m_r[4], l_r[4];   // l_r: per-lane PARTIAL sums (reduced in epilogue)
#pragma unroll
    for (int r = 0; r < 4; r++) { m_r[r] = -3e38f; l_r[r] = 0.f; }

    for (int kt = 0; kt <= qt; kt++) {
      int k0 = kt * AT_BK;
      size_t tokbase = (size_t)(b * S + k0);
      // ---- stage K (nope+pe) and V^T with swizzled per-lane global chunk ----
#pragma unroll
      for (int c = 0; c < 4; c++) {  // Ksn: 4 rows/call, 16 chunks/row
        int row = w * 16 + c * 4 + (lane >> 4);
        int cg = (lane & 15) ^ (row & 7);
        gld_lds16(kvb + (tokbase + row) * 4096 + h * 256 + cg * 8,
                  &Ksn[(w * 16 + c * 4) * 128]);
      }
#pragma unroll
      for (int c = 0; c < 2; c++) {  // Ksp: 8 rows/call, 8 chunks/row
        int row = w * 16 + c * 8 + (lane >> 3);
        int cg = (lane & 7) ^ (row & 7);
        gld_lds16(kpe + (tokbase + row) * kpe_stride + cg * 8,
                  &Ksp[(w * 16 + c * 8) * 64]);
      }
#pragma unroll
      for (int c = 0; c < 4; c++) {  // Vts: 8 vd-rows/call, 8 chunks/row
        int vd = w * 32 + c * 8 + (lane >> 3);
        int cg = (lane & 7) ^ (vd & 7);
        gld_lds16(vt + ((size_t)((b * 16 + h) * 128) + vd) * S + k0 + cg * 8,
                  &Vts[(w * 32 + c * 8) * 64]);
      }
      __syncthreads();

      // ---- S = Q K^T for wave's 16 rows x 64 keys ----
      floatx4 accs[4];
#pragma unroll
      for (int nt = 0; nt < 4; nt++) accs[nt] = (floatx4){0.f, 0.f, 0.f, 0.f};
      __builtin_amdgcn_s_setprio(1);
#pragma unroll
      for (int nt = 0; nt < 4; nt++) {
#pragma unroll
        for (int ks = 0; ks < 4; ks++) {
          short8 bf = *(const short8*)&Ksn[(nt * 16 + fr) * 128 + ((ks * 4 + fq) ^ fs) * 8];
          accs[nt] = __builtin_amdgcn_mfma_f32_16x16x32_bf16(qfrag[ks], bf, accs[nt], 0, 0, 0);
        }
#pragma unroll
        for (int ks = 0; ks < 2; ks++) {
          short8 bf = *(const short8*)&Ksp[(nt * 16 + fr) * 64 + ((ks * 4 + fq) ^ fs) * 8];
          accs[nt] = __builtin_amdgcn_mfma_f32_16x16x32_bf16(qfrag[4 + ks], bf, accs[nt], 0, 0, 0);
        }
      }
      __builtin_amdgcn_s_setprio(0);

      // ---- scale + causal mask (diagonal tile only) ----
      bool diag = (kt == qt);
#pragma unroll
      for (int nt = 0; nt < 4; nt++)
#pragma unroll
        for (int r = 0; r < 4; r++) {
          float s = accs[nt][r] * scale;
          if (diag) {
            int col = nt * 16 + fr;
            int row = fq * 4 + r;
            if (k0 + col > q0 + w * 16 + row) s = -3e38f;
          }
          accs[nt][r] = s;
        }

      // ---- online softmax with defer-rescale (T13, THR=8) ----
      float mx4[4];
      int grow = 0;
#pragma unroll
      for (int r = 0; r < 4; r++) {
        float mx = fmaxf(fmaxf(accs[0][r], accs[1][r]), fmaxf(accs[2][r], accs[3][r]));
        mx = fmaxf(mx, __shfl_xor(mx, 1));
        mx = fmaxf(mx, __shfl_xor(mx, 2));
        mx = fmaxf(mx, __shfl_xor(mx, 4));
        mx = fmaxf(mx, __shfl_xor(mx, 8));
        mx4[r] = mx;
        grow |= (mx > m_r[r] + 8.f) ? 1 : 0;
      }
      bool resc = __any(grow);   // wave-uniform decision
      float alpha[4];
      if (resc) {
#pragma unroll
        for (int r = 0; r < 4; r++) {
          float mnew = fmaxf(m_r[r], mx4[r]);
          alpha[r] = __expf(m_r[r] - mnew);
          m_r[r] = mnew;
          l_r[r] *= alpha[r];
        }
      }
#pragma unroll
      for (int nt = 0; nt < 4; nt++)
#pragma unroll
        for (int r = 0; r < 4; r++) {
          float pv = __expf(accs[nt][r] - m_r[r]);   // bounded by e^8 when deferred
          l_r[r] += pv;
          int row_p = w * 16 + fq * 4 + r;
          int col = nt * 16 + fr;
          Ps[row_p * 64 + (((col >> 3) ^ (row_p & 7)) * 8) + (col & 7)] = f2bf(pv);
        }
      __syncthreads();   // Ps visible to PV reads (r8: removing this cost +8us)

      // ---- O = O*alpha + P V ----
      if (resc) {
#pragma unroll
        for (int j = 0; j < 8; j++)
#pragma unroll
          for (int r = 0; r < 4; r++) acc_o[j][r] *= alpha[r];
      }
      short8 pf0 = *(const short8*)&Ps[(w * 16 + fr) * 64 + (fq ^ fs) * 8];
      short8 pf1 = *(const short8*)&Ps[(w * 16 + fr) * 64 + ((4 + fq) ^ fs) * 8];
      __builtin_amdgcn_s_setprio(1);
#pragma unroll
      for (int j = 0; j < 8; j++) {
        short8 v0 = *(const short8*)&Vts[(j * 16 + fr) * 64 + (fq ^ fs) * 8];
        short8 v1 = *(const short8*)&Vts[(j * 16 + fr) * 64 + ((4 + fq) ^ fs) * 8];
        acc_o[j] = __builtin_amdgcn_mfma_f32_16x16x32_bf16(pf0, v0, acc_o[j], 0, 0, 0);
        acc_o[j] = __builtin_amdgcn_mfma_f32_16x16x32_bf16(pf1, v1, acc_o[j], 0, 0, 0);
      }
      __builtin_amdgcn_s_setprio(0);
      __syncthreads();   // before next tile's staging overwrites LDS
    }

    // ---- epilogue: reduce per-lane l partials across the row's 16 lanes ----
    float inv_l[4];
#pragma unroll
    for (int r = 0; r < 4; r++) {
      float sm = l_r[r];
      sm += __shfl_xor(sm, 1);
      sm += __shfl_xor(sm, 2);
      sm += __shfl_xor(sm, 4);
      sm += __shfl_xor(sm, 8);
      inv_l[r] = 1.f / sm;
    }
#pragma unroll
    for (int j = 0; j < 8; j++)
#pragma unroll
      for (int r = 0; r < 4; r++) {
        size_t row = (size_t)(b * S + q0 + w * 16 + fq * 4 + r);
        at[row * 2048 + h * 128 + j * 16 + fr] = f2bf(acc_o[j][r] * inv_l[r]);
      }
  }
}

// ---------------------------------------------------------------------------
extern "C" void kernel_launch(void* const* d_in, const int* in_sizes, int n_in,
                              void* d_out, int out_size, void* d_ws, size_t ws_size,
                              hipStream_t stream) {
  (void)in_sizes; (void)n_in; (void)out_size; (void)ws_size;
  const float* x     = (const float*)d_in[0];
  const float* cosb  = (const float*)d_in[1];
  const float* sinb  = (const float*)d_in[2];
  const float* wq_a  = (const float*)d_in[3];
  const float* qnw   = (const float*)d_in[4];
  const float* wq_b  = (const float*)d_in[5];
  const float* wkv_a = (const float*)d_in[6];
  const float* kvnw  = (const float*)d_in[7];
  const float* wkv_b = (const float*)d_in[8];
  const float* wo    = (const float*)d_in[9];
  float* out = (float*)d_out;
  const int B = 2, S = 2048, T = B * S;

  char* wsb = (char*)d_ws;
  size_t off = 0;
  u16* xb   = (u16*)(wsb + off); off += (size_t)T * 2048 * 2;
  u16* wcat = (u16*)(wsb + off); off += (size_t)2304 * 2048 * 2;  // wq_a|wkv_a|pad
  u16* wqbb = (u16*)(wsb + off); off += (size_t)3072 * 1536 * 2;
  u16* wkbb = (u16*)(wsb + off); off += (size_t)4096 * 512 * 2;
  u16* wob  = (u16*)(wsb + off); off += (size_t)2048 * 2048 * 2;
  u16* qkv  = (u16*)(wsb + off); off += (size_t)T * 2304 * 2;     // qa|kv|kpe|pad
  u16* qf   = (u16*)(wsb + off); off += (size_t)T * 3072 * 2;
  u16* kvb  = (u16*)(wsb + off); off += (size_t)T * 4096 * 2;
  u16* at   = (u16*)(wsb + off); off += (size_t)T * 2048 * 2;
  u16* vt   = xb;   // reuse: xb dead after GEMM 1; same size (T*2048)

  // 0) all repacks in one dispatch
  repack_all_k<<<dim3(8192, 5), 256, 0, stream>>>(
      x, wq_a, wkv_a, wq_b, wkv_b, wo, xb, wcat, wqbb, wkbb, wob);

  // 1) qkv = xb @ [wq_a;wkv_a;pad]^T   [T,2304]  (qa | kv | kpe | pad)
  gemm256_k<0><<<dim3(2304 / 256, T / 256), 512, 0, stream>>>(xb, 2048, wcat, 2048, qkv, 2304, 2048);
  // 2) fused: rmsnorm(qa), rmsnorm(kv), rope(kpe)
  normrope_k<<<T, 256, 0, stream>>>(qkv, qnw, kvnw, cosb, sinb, S);
  // 3) merged: qf = qa @ wq_b^T [T,3072] (+ fused q-RoPE on accumulator)
  //    AND kvb = kv @ wkv_b^T [T,4096]
  gemm256_dual<<<dim3(3072 / 256 + 4096 / 256, T / 256), 512, 0, stream>>>(
      qkv, 2304, wqbb, 1536, qf, 3072, 1536, 3072 / 256,
      qkv + 1536, 2304, wkbb, 512, kvb, 4096, 512,
      cosb, sinb, S - 1);
  // 4) V transpose (vt overlays dead xb)  [rope_k dispatch eliminated]
  vtrans_k<<<dim3(S / 64, 16, B), 256, 0, stream>>>(kvb, vt, S);
  // 5) MFMA flash attention (paired q-tiles, XCD-grouped, r3 schedule)
  attn_mfma<<<dim3((S / 128) * 32), 256, 0, stream>>>(qf, kvb, qkv + 2048, 2304, vt, at, S);
  // 6) out = at @ wo^T [T,2048] fp32
  gemm256_k<1><<<dim3(2048 / 256, T / 256), 512, 0, stream>>>(at, 2048, wob, 2048, out, 2048, 2048);
}

// Round 12
// 453.830 us; speedup vs baseline: 1.0251x; 1.0145x over previous
//
#include <hip/hip_runtime.h>

typedef unsigned short u16;
typedef __attribute__((ext_vector_type(8))) short short8;   // 8 bf16 = 4 VGPRs
typedef __attribute__((ext_vector_type(4))) float floatx4;

__device__ __forceinline__ float bf2f(u16 u) {
  union { unsigned int i; float f; } v; v.i = ((unsigned int)u) << 16; return v.f;
}
__device__ __forceinline__ u16 f2bf(float f) {
  union { float f; unsigned int i; } v; v.f = f;
  unsigned int u = v.i;
  u += 0x7fffu + ((u >> 16) & 1u);   // RNE
  return (u16)(u >> 16);
}

__device__ __forceinline__ void gld_lds16(const void* g, void* l) {
  __builtin_amdgcn_global_load_lds(
      (const __attribute__((address_space(1))) unsigned int*)g,
      (__attribute__((address_space(3))) unsigned int*)l, 16, 0, 0);
}

#define SBAR()   __builtin_amdgcn_s_barrier()
#define SCHED0() __builtin_amdgcn_sched_barrier(0)

// ---------------------------------------------------------------------------
// One-shot repack: blockIdx.y selects region.
//  0: x      [4096,2048] -> xb
//  1: wcat   rows 0..1535 wq_a, 1536..2111 wkv_a, 2112..2303 zero  (cols 2048)
//  2: wq_b   [3072,1536] -> wqbb
//  3: wkv_b  [4096,512]  -> wkbb
//  4: wo     [2048,2048] -> wob
// ---------------------------------------------------------------------------
__global__ __launch_bounds__(256) void repack_all_k(
    const float* __restrict__ x, const float* __restrict__ wqa,
    const float* __restrict__ wkva, const float* __restrict__ wqb,
    const float* __restrict__ wkvb, const float* __restrict__ wo,
    u16* __restrict__ xb, u16* __restrict__ wcat, u16* __restrict__ wqbb,
    u16* __restrict__ wkbb, u16* __restrict__ wob) {
  long i = ((long)blockIdx.x * 256 + threadIdx.x) * 4;
  int region = blockIdx.y;
  const float* s = nullptr; u16* d = nullptr; long n = 0;
  switch (region) {
    case 0: s = x;    d = xb;   n = 4096L * 2048; break;
    case 1: s = nullptr; d = wcat; n = 2304L * 2048; break;
    case 2: s = wqb;  d = wqbb; n = 3072L * 1536; break;
    case 3: s = wkvb; d = wkbb; n = 4096L * 512;  break;
    case 4: s = wo;   d = wob;  n = 2048L * 2048; break;
  }
  if (i >= n) return;
  float4 v;
  if (region == 1) {  // concatenated + padded (chunks never cross rows: 2048%4==0)
    long r = i >> 11, c = i & 2047;
    if (r < 1536)      v = *(const float4*)(wqa + r * 2048 + c);
    else if (r < 2112) v = *(const float4*)(wkva + (r - 1536) * 2048 + c);
    else               v = (float4){0.f, 0.f, 0.f, 0.f};
  } else {
    v = *(const float4*)(s + i);
  }
  d[i + 0] = f2bf(v.x); d[i + 1] = f2bf(v.y);
  d[i + 2] = f2bf(v.z); d[i + 3] = f2bf(v.w);
}

// ---------------------------------------------------------------------------
// 256x256 8-phase GEMM (m201 template, plain HIP). C = A[M,K] * W[N,K]^T.
// 512 threads (8 waves, 2Mx4N), BK=64, 2 K-tiles/iter, LDS 128 KiB dbuf,
// XOR-granule swizzle, counted vmcnt(4) at phases 4/8, setprio on MFMA.
// ROPE=1: fused q-RoPE on 64-col windows where ((bn+wc*64)/64)%3==2.
// VTR=1:  V-transpose epilogue — each 256-col tile is one head; waves wc>=2
//         own V cols (vd=col&127); a lane's 4 acc rows are 4 consecutive
//         tokens -> one 8B ushort4 store into vt[((b*16+h)*128+vd)*S+tok].
//         Replaces the standalone vtrans dispatch AND the kvb V-col writes.
// Requires: M%256==0, N%256==0, K%128==0.
// ---------------------------------------------------------------------------
#define GPHASE(LAc, LBc, QQ, STAGE_STMT, WAIT_STMT)                              \
  {                                                                              \
    short8 a00 = *(const short8*)&(LAc)[agbase + (2*(QQ)) * 1024 + g0];          \
    short8 a01 = *(const short8*)&(LAc)[agbase + (2*(QQ)) * 1024 + g1];          \
    short8 a10 = *(const short8*)&(LAc)[agbase + (2*(QQ)+1) * 1024 + g0];        \
    short8 a11 = *(const short8*)&(LAc)[agbase + (2*(QQ)+1) * 1024 + g1];        \
    if ((QQ) == 0) {                                                             \
      _Pragma("unroll")                                                          \
      for (int fj = 0; fj < 4; ++fj) {                                           \
        bfrg[fj][0] = *(const short8*)&(LBc)[bgbase + fj * 1024 + g0];           \
        bfrg[fj][1] = *(const short8*)&(LBc)[bgbase + fj * 1024 + g1];           \
      }                                                                          \
    }                                                                            \
    STAGE_STMT;                                                                  \
    WAIT_STMT;                                                                   \
    SCHED0();                                                                    \
    SBAR();                                                                      \
    asm volatile("s_waitcnt lgkmcnt(0)" ::: "memory");                           \
    SCHED0();                                                                    \
    __builtin_amdgcn_s_setprio(1);                                               \
    _Pragma("unroll")                                                            \
    for (int fj = 0; fj < 4; ++fj) {                                             \
      acc[2*(QQ)][fj]   = __builtin_amdgcn_mfma_f32_16x16x32_bf16(a00, bfrg[fj][0], acc[2*(QQ)][fj],   0, 0, 0); \
      acc[2*(QQ)][fj]   = __builtin_amdgcn_mfma_f32_16x16x32_bf16(a01, bfrg[fj][1], acc[2*(QQ)][fj],   0, 0, 0); \
      acc[2*(QQ)+1][fj] = __builtin_amdgcn_mfma_f32_16x16x32_bf16(a10, bfrg[fj][0], acc[2*(QQ)+1][fj], 0, 0, 0); \
      acc[2*(QQ)+1][fj] = __builtin_amdgcn_mfma_f32_16x16x32_bf16(a11, bfrg[fj][1], acc[2*(QQ)+1][fj], 0, 0, 0); \
    }                                                                            \
    __builtin_amdgcn_s_setprio(0);                                               \
    SCHED0();                                                                    \
    SBAR();                                                                      \
  }

template <int OUT_F32, int ROPE, int VTR>
__device__ __forceinline__ void gemm256_tile(
    const u16* __restrict__ A, int lda, const u16* __restrict__ W, int ldw,
    void* __restrict__ Cv, int ldc, int K, int bm, int bn,
    u16* __restrict__ LA, u16* __restrict__ LB,
    const float* __restrict__ cosb, const float* __restrict__ sinb, int smask,
    u16* __restrict__ vtr) {
  int tid = threadIdx.x;
  int lane = tid & 63, w = tid >> 6;
  int wr = w >> 2, wc = w & 3;            // wave grid: 2 (M) x 4 (N)
  int fr = lane & 15, fq = lane >> 4;     // fragment row / k-quad

  int srow = lane >> 3;                   // 0..7
  int sgl  = (lane & 7) ^ srow;           // pre-swizzled source granule

  int agbase = (wr * 128 + fr) * 64;
  int bgbase = (wc * 64 + fr) * 64;
  int g0 = ((0 * 4 + fq) ^ (fr & 7)) * 8;
  int g1 = ((1 * 4 + fq) ^ (fr & 7)) * 8;

  floatx4 acc[8][4];
#pragma unroll
  for (int i = 0; i < 8; i++)
#pragma unroll
    for (int j = 0; j < 4; j++) acc[i][j] = (floatx4){0.f, 0.f, 0.f, 0.f};

  auto stA = [&](int buf, int kt, int half) {
#pragma unroll
    for (int j = 0; j < 2; ++j) {
      int rbase = half * 128 + (w * 2 + j) * 8;
      gld_lds16(A + (size_t)(bm + rbase + srow) * lda + kt * 64 + sgl * 8,
                (void*)&LA[buf * 16384 + rbase * 64]);
    }
  };
  auto stB = [&](int buf, int kt, int half) {
#pragma unroll
    for (int j = 0; j < 2; ++j) {
      int rbase = half * 128 + (w * 2 + j) * 8;
      gld_lds16(W + (size_t)(bn + rbase + srow) * ldw + kt * 64 + sgl * 8,
                (void*)&LB[buf * 16384 + rbase * 64]);
    }
  };

  const u16* LA0 = LA;           const u16* LB0 = LB;
  const u16* LA1 = LA + 16384;   const u16* LB1 = LB + 16384;

  stB(0, 0, 0); stB(0, 0, 1);
  stA(0, 0, 0); stA(0, 0, 1);
  stB(1, 1, 0); stB(1, 1, 1);
  asm volatile("s_waitcnt vmcnt(4)" ::: "memory");
  SCHED0();
  SBAR();

  int NI = K >> 7;   // 2 K-tiles (BK=64) per iteration
  for (int i = 0; i < NI; ++i) {
    bool notlast = (i + 1 < NI);
    int t0 = 2 * i;
    {
      short8 bfrg[4][2];
      GPHASE(LA0, LB0, 0, stA(1, t0 + 1, 0), );
      GPHASE(LA0, LB0, 1, stA(1, t0 + 1, 1), );
      GPHASE(LA0, LB0, 2, if (notlast) stB(0, t0 + 2, 0), );
      GPHASE(LA0, LB0, 3, if (notlast) stB(0, t0 + 2, 1),
             if (notlast) { asm volatile("s_waitcnt vmcnt(4)" ::: "memory"); }
             else         { asm volatile("s_waitcnt vmcnt(0)" ::: "memory"); });
    }
    {
      short8 bfrg[4][2];
      GPHASE(LA1, LB1, 0, if (notlast) stA(0, t0 + 2, 0), );
      GPHASE(LA1, LB1, 1, if (notlast) stA(0, t0 + 2, 1), );
      GPHASE(LA1, LB1, 2, if (notlast) stB(1, t0 + 3, 0), );
      GPHASE(LA1, LB1, 3, if (notlast) stB(1, t0 + 3, 1),
             if (notlast) { asm volatile("s_waitcnt vmcnt(4)" ::: "memory"); });
    }
  }

  int cr = (lane >> 4) * 4, cc = lane & 15;

  // ---- fused q-RoPE on the accumulator (rope window: colwin % 3 == 2) ----
  if (ROPE) {
    int cw = (bn + wc * 64) >> 6;
    if (cw % 3 == 2) {
#pragma unroll
      for (int fi = 0; fi < 8; ++fi)
#pragma unroll
        for (int r = 0; r < 4; ++r) {
          int row = bm + wr * 128 + fi * 16 + cr + r;
          int pos = row & smask;               // token position (S power of 2)
          const float* cb = cosb + pos * 64;
          const float* sb = sinb + pos * 64;
#pragma unroll
          for (int fj = 0; fj < 2; ++fj) {     // pairs (fj, fj+2) = (i, i+32)
            int i1 = fj * 16 + cc;
            float x1 = acc[fi][fj][r], x2 = acc[fi][fj + 2][r];
            acc[fi][fj][r]     = x1 * cb[i1] - x2 * sb[i1];
            acc[fi][fj + 2][r] = x2 * cb[i1 + 32] + x1 * sb[i1 + 32];
          }
        }
    }
  }

  // ---- VTR epilogue: V half (wc>=2) -> transposed vt; K half -> normal ----
  if (VTR && wc >= 2) {
    int h = bn >> 8;                       // one head per 256-col tile
#pragma unroll
    for (int fi = 0; fi < 8; ++fi)
#pragma unroll
      for (int fj = 0; fj < 4; ++fj) {
        int col = bn + wc * 64 + fj * 16 + cc;
        int vd = col & 127;                // V cols: within-head 128..255
        int row0 = bm + wr * 128 + fi * 16 + cr;   // 4 consecutive tokens
        int b = row0 >> 11, tok = row0 & 2047;     // S = 2048
        ushort4 pk;
        pk.x = f2bf(acc[fi][fj][0]);
        pk.y = f2bf(acc[fi][fj][1]);
        pk.z = f2bf(acc[fi][fj][2]);
        pk.w = f2bf(acc[fi][fj][3]);
        *(ushort4*)(vtr + ((size_t)((b * 16 + h) * 128 + vd)) * 2048 + tok) = pk;
      }
    return;
  }

#pragma unroll
  for (int fi = 0; fi < 8; ++fi)
#pragma unroll
    for (int fj = 0; fj < 4; ++fj) {
      int col = bn + wc * 64 + fj * 16 + cc;
#pragma unroll
      for (int r = 0; r < 4; ++r) {
        size_t row = (size_t)(bm + wr * 128 + fi * 16 + cr + r);
        if (OUT_F32) ((float*)Cv)[row * ldc + col] = acc[fi][fj][r];
        else         ((u16*)Cv)[row * ldc + col] = f2bf(acc[fi][fj][r]);
      }
    }
}

template <int OUT_F32>
__global__ __launch_bounds__(512, 2) void gemm256_k(
    const u16* __restrict__ A, int lda,
    const u16* __restrict__ W, int ldw,
    void* __restrict__ Cv, int ldc, int K) {
  __shared__ __align__(16) u16 LAs[2][256 * 64];
  __shared__ __align__(16) u16 LBs[2][256 * 64];
  gemm256_tile<OUT_F32, 0, 0>(A, lda, W, ldw, Cv, ldc, K,
                              blockIdx.y * 256, blockIdx.x * 256,
                              &LAs[0][0], &LBs[0][0], nullptr, nullptr, 0, nullptr);
}

// Two GEMMs sharing one dispatch: blockIdx.x < nt1 -> GEMM1 (qf, fused rope),
// else GEMM2 (kvb; V half written transposed to vt, K half normal).
__global__ __launch_bounds__(512, 2) void gemm256_dual(
    const u16* __restrict__ A1, int lda1, const u16* __restrict__ W1, int ldw1,
    u16* __restrict__ C1, int ldc1, int K1, int nt1,
    const u16* __restrict__ A2, int lda2, const u16* __restrict__ W2, int ldw2,
    u16* __restrict__ C2, int ldc2, int K2,
    const float* __restrict__ cosb, const float* __restrict__ sinb, int smask,
    u16* __restrict__ vtr) {
  __shared__ __align__(16) u16 LAs[2][256 * 64];
  __shared__ __align__(16) u16 LBs[2][256 * 64];
  int bx = blockIdx.x;
  if (bx < nt1)
    gemm256_tile<0, 1, 0>(A1, lda1, W1, ldw1, C1, ldc1, K1,
                          blockIdx.y * 256, bx * 256, &LAs[0][0], &LBs[0][0],
                          cosb, sinb, smask, nullptr);
  else
    gemm256_tile<0, 0, 1>(A2, lda2, W2, ldw2, C2, ldc2, K2,
                          blockIdx.y * 256, (bx - nt1) * 256, &LAs[0][0], &LBs[0][0],
                          nullptr, nullptr, 0, vtr);
}

// ---------------------------------------------------------------------------
// Fused per-row: rmsnorm(qa cols 0..1535), rmsnorm(kv cols 1536..2047),
// rope(kpe cols 2048..2111). One block per row of qkv [T, 2304].
// ---------------------------------------------------------------------------
__global__ __launch_bounds__(256) void normrope_k(
    u16* __restrict__ qkv, const float* __restrict__ qnw,
    const float* __restrict__ kvnw, const float* __restrict__ cosb,
    const float* __restrict__ sinb, int S) {
  int row = blockIdx.x, tid = threadIdx.x;
  u16* p = qkv + (size_t)row * 2304;
  float s1 = 0.f, s2 = 0.f;
#pragma unroll
  for (int it = 0; it < 6; it++) { float v = bf2f(p[tid + 256 * it]); s1 += v * v; }
#pragma unroll
  for (int it = 0; it < 2; it++) { float v = bf2f(p[1536 + tid + 256 * it]); s2 += v * v; }
  for (int off = 32; off > 0; off >>= 1) {
    s1 += __shfl_down(s1, off);
    s2 += __shfl_down(s2, off);
  }
  __shared__ float red1[4], red2[4];
  if ((tid & 63) == 0) { red1[tid >> 6] = s1; red2[tid >> 6] = s2; }
  __syncthreads();
  float inv1 = rsqrtf((red1[0] + red1[1] + red1[2] + red1[3]) / 1536.f + 1e-6f);
  float inv2 = rsqrtf((red2[0] + red2[1] + red2[2] + red2[3]) / 512.f + 1e-6f);
#pragma unroll
  for (int it = 0; it < 6; it++) {
    int i = tid + 256 * it;
    p[i] = f2bf(bf2f(p[i]) * inv1 * qnw[i]);
  }
#pragma unroll
  for (int it = 0; it < 2; it++) {
    int i = tid + 256 * it;
    p[1536 + i] = f2bf(bf2f(p[1536 + i]) * inv2 * kvnw[i]);
  }
  if (tid < 32) {
    int pos = row % S;
    float c1 = cosb[pos * 64 + tid];
    float c2 = cosb[pos * 64 + tid + 32];
    float sn1 = sinb[pos * 64 + tid];
    float sn2 = sinb[pos * 64 + tid + 32];
    float x1 = bf2f(p[2048 + tid]), x2 = bf2f(p[2048 + tid + 32]);
    p[2048 + tid]      = f2bf(x1 * c1 - x2 * sn1);
    p[2048 + tid + 32] = f2bf(x2 * c2 + x1 * sn2);
  }
}

// ---------------------------------------------------------------------------
// MFMA flash attention. PAIRED q-tiles (uniform work: every block exactly
// NT+1 k-iterations), XCD-grouped dispatch, T5 setprio, T13 defer-rescale,
// __expf fast path. Round-3 schedule (3 barriers/iter) — measured optimum;
// r4/r6/r7/r8 perturbations all regressed.
// ---------------------------------------------------------------------------
#define AT_BK 64
__global__ __launch_bounds__(256) void attn_mfma(
    const u16* __restrict__ qf, const u16* __restrict__ kvb,
    const u16* __restrict__ kpe, int kpe_stride, const u16* __restrict__ vt,
    u16* __restrict__ at, int S) {
  int id = blockIdx.x;
  int pair = id >> 5, hb = id & 31;
  int h = hb & 15, b = hb >> 4;
  int NT = S / AT_BK;
  int tid = threadIdx.x, lane = tid & 63, w = tid >> 6;
  int fr = lane & 15, fq = lane >> 4;   // fragment row / k-quad
  int fs = fr & 7;                      // swizzle key for reads

  __shared__ __align__(16) u16 Ksn[AT_BK * 128];  // [key][16 chunks]
  __shared__ __align__(16) u16 Ksp[AT_BK * 64];   // [key][8 chunks]
  __shared__ __align__(16) u16 Vts[128 * AT_BK];  // [vd][8 chunks]
  __shared__ __align__(16) u16 Ps[64 * AT_BK];    // [qrow][8 chunks]

  const float scale = 0.07216878364870323f;  // 192^-0.5

  for (int p = 0; p < 2; p++) {
    int qt = p ? (NT - 1 - pair) : pair;
    int q0 = qt * 64;

    // Q fragments direct from global: A[m=fr][k=fq*8+j], 6 k-steps of 32
    short8 qfrag[6];
    {
      const u16* qrow = qf + (size_t)(b * S + q0 + w * 16 + fr) * 3072 + h * 192 + fq * 8;
#pragma unroll
      for (int ks = 0; ks < 6; ks++) qfrag[ks] = *(const short8*)(qrow + ks * 32);
    }

    floatx4 acc_o[8];
#pragma unroll
    for (int j = 0; j < 8; j++) acc_o[j] = (floatx4){0.f, 0.f, 0.f, 0.f};
    float m_r[4], l_r[4];   // l_r: per-lane PARTIAL sums (reduced in epilogue)
#pragma unroll
    for (int r = 0; r < 4; r++) { m_r[r] = -3e38f; l_r[r] = 0.f; }

    for (int kt = 0; kt <= qt; kt++) {
      int k0 = kt * AT_BK;
      size_t tokbase = (size_t)(b * S + k0);
      // ---- stage K (nope+pe) and V^T with swizzled per-lane global chunk ----
#pragma unroll
      for (int c = 0; c < 4; c++) {  // Ksn: 4 rows/call, 16 chunks/row
        int row = w * 16 + c * 4 + (lane >> 4);
        int cg = (lane & 15) ^ (row & 7);
        gld_lds16(kvb + (tokbase + row) * 4096 + h * 256 + cg * 8,
                  &Ksn[(w * 16 + c * 4) * 128]);
      }
#pragma unroll
      for (int c = 0; c < 2; c++) {  // Ksp: 8 rows/call, 8 chunks/row
        int row = w * 16 + c * 8 + (lane >> 3);
        int cg = (lane & 7) ^ (row & 7);
        gld_lds16(kpe + (tokbase + row) * kpe_stride + cg * 8,
                  &Ksp[(w * 16 + c * 8) * 64]);
      }
#pragma unroll
      for (int c = 0; c < 4; c++) {  // Vts: 8 vd-rows/call, 8 chunks/row
        int vd = w * 32 + c * 8 + (lane >> 3);
        int cg = (lane & 7) ^ (vd & 7);
        gld_lds16(vt + ((size_t)((b * 16 + h) * 128) + vd) * S + k0 + cg * 8,
                  &Vts[(w * 32 + c * 8) * 64]);
      }
      __syncthreads();

      // ---- S = Q K^T for wave's 16 rows x 64 keys ----
      floatx4 accs[4];
#pragma unroll
      for (int nt = 0; nt < 4; nt++) accs[nt] = (floatx4){0.f, 0.f, 0.f, 0.f};
      __builtin_amdgcn_s_setprio(1);
#pragma unroll
      for (int nt = 0; nt < 4; nt++) {
#pragma unroll
        for (int ks = 0; ks < 4; ks++) {
          short8 bf = *(const short8*)&Ksn[(nt * 16 + fr) * 128 + ((ks * 4 + fq) ^ fs) * 8];
          accs[nt] = __builtin_amdgcn_mfma_f32_16x16x32_bf16(qfrag[ks], bf, accs[nt], 0, 0, 0);
        }
#pragma unroll
        for (int ks = 0; ks < 2; ks++) {
          short8 bf = *(const short8*)&Ksp[(nt * 16 + fr) * 64 + ((ks * 4 + fq) ^ fs) * 8];
          accs[nt] = __builtin_amdgcn_mfma_f32_16x16x32_bf16(qfrag[4 + ks], bf, accs[nt], 0, 0, 0);
        }
      }
      __builtin_amdgcn_s_setprio(0);

      // ---- scale + causal mask (diagonal tile only) ----
      bool diag = (kt == qt);
#pragma unroll
      for (int nt = 0; nt < 4; nt++)
#pragma unroll
        for (int r = 0; r < 4; r++) {
          float s = accs[nt][r] * scale;
          if (diag) {
            int col = nt * 16 + fr;
            int row = fq * 4 + r;
            if (k0 + col > q0 + w * 16 + row) s = -3e38f;
          }
          accs[nt][r] = s;
        }

      // ---- online softmax with defer-rescale (T13, THR=8) ----
      float mx4[4];
      int grow = 0;
#pragma unroll
      for (int r = 0; r < 4; r++) {
        float mx = fmaxf(fmaxf(accs[0][r], accs[1][r]), fmaxf(accs[2][r], accs[3][r]));
        mx = fmaxf(mx, __shfl_xor(mx, 1));
        mx = fmaxf(mx, __shfl_xor(mx, 2));
        mx = fmaxf(mx, __shfl_xor(mx, 4));
        mx = fmaxf(mx, __shfl_xor(mx, 8));
        mx4[r] = mx;
        grow |= (mx > m_r[r] + 8.f) ? 1 : 0;
      }
      bool resc = __any(grow);   // wave-uniform decision
      float alpha[4];
      if (resc) {
#pragma unroll
        for (int r = 0; r < 4; r++) {
          float mnew = fmaxf(m_r[r], mx4[r]);
          alpha[r] = __expf(m_r[r] - mnew);
          m_r[r] = mnew;
          l_r[r] *= alpha[r];
        }
      }
#pragma unroll
      for (int nt = 0; nt < 4; nt++)
#pragma unroll
        for (int r = 0; r < 4; r++) {
          float pv = __expf(accs[nt][r] - m_r[r]);   // bounded by e^8 when deferred
          l_r[r] += pv;
          int row_p = w * 16 + fq * 4 + r;
          int col = nt * 16 + fr;
          Ps[row_p * 64 + (((col >> 3) ^ (row_p & 7)) * 8) + (col & 7)] = f2bf(pv);
        }
      __syncthreads();   // Ps visible to PV reads (r8: removing this cost +8us)

      // ---- O = O*alpha + P V ----
      if (resc) {
#pragma unroll
        for (int j = 0; j < 8; j++)
#pragma unroll
          for (int r = 0; r < 4; r++) acc_o[j][r] *= alpha[r];
      }
      short8 pf0 = *(const short8*)&Ps[(w * 16 + fr) * 64 + (fq ^ fs) * 8];
      short8 pf1 = *(const short8*)&Ps[(w * 16 + fr) * 64 + ((4 + fq) ^ fs) * 8];
      __builtin_amdgcn_s_setprio(1);
#pragma unroll
      for (int j = 0; j < 8; j++) {
        short8 v0 = *(const short8*)&Vts[(j * 16 + fr) * 64 + (fq ^ fs) * 8];
        short8 v1 = *(const short8*)&Vts[(j * 16 + fr) * 64 + ((4 + fq) ^ fs) * 8];
        acc_o[j] = __builtin_amdgcn_mfma_f32_16x16x32_bf16(pf0, v0, acc_o[j], 0, 0, 0);
        acc_o[j] = __builtin_amdgcn_mfma_f32_16x16x32_bf16(pf1, v1, acc_o[j], 0, 0, 0);
      }
      __builtin_amdgcn_s_setprio(0);
      __syncthreads();   // before next tile's staging overwrites LDS
    }

    // ---- epilogue: reduce per-lane l partials across the row's 16 lanes ----
    float inv_l[4];
#pragma unroll
    for (int r = 0; r < 4; r++) {
      float sm = l_r[r];
      sm += __shfl_xor(sm, 1);
      sm += __shfl_xor(sm, 2);
      sm += __shfl_xor(sm, 4);
      sm += __shfl_xor(sm, 8);
      inv_l[r] = 1.f / sm;
    }
#pragma unroll
    for (int j = 0; j < 8; j++)
#pragma unroll
      for (int r = 0; r < 4; r++) {
        size_t row = (size_t)(b * S + q0 + w * 16 + fq * 4 + r);
        at[row * 2048 + h * 128 + j * 16 + fr] = f2bf(acc_o[j][r] * inv_l[r]);
      }
  }
}

// ---------------------------------------------------------------------------
extern "C" void kernel_launch(void* const* d_in, const int* in_sizes, int n_in,
                              void* d_out, int out_size, void* d_ws, size_t ws_size,
                              hipStream_t stream) {
  (void)in_sizes; (void)n_in; (void)out_size; (void)ws_size;
  const float* x     = (const float*)d_in[0];
  const float* cosb  = (const float*)d_in[1];
  const float* sinb  = (const float*)d_in[2];
  const float* wq_a  = (const float*)d_in[3];
  const float* qnw   = (const float*)d_in[4];
  const float* wq_b  = (const float*)d_in[5];
  const float* wkv_a = (const float*)d_in[6];
  const float* kvnw  = (const float*)d_in[7];
  const float* wkv_b = (const float*)d_in[8];
  const float* wo    = (const float*)d_in[9];
  float* out = (float*)d_out;
  const int B = 2, S = 2048, T = B * S;

  char* wsb = (char*)d_ws;
  size_t off = 0;
  u16* xb   = (u16*)(wsb + off); off += (size_t)T * 2048 * 2;
  u16* wcat = (u16*)(wsb + off); off += (size_t)2304 * 2048 * 2;  // wq_a|wkv_a|pad
  u16* wqbb = (u16*)(wsb + off); off += (size_t)3072 * 1536 * 2;
  u16* wkbb = (u16*)(wsb + off); off += (size_t)4096 * 512 * 2;
  u16* wob  = (u16*)(wsb + off); off += (size_t)2048 * 2048 * 2;
  u16* qkv  = (u16*)(wsb + off); off += (size_t)T * 2304 * 2;     // qa|kv|kpe|pad
  u16* qf   = (u16*)(wsb + off); off += (size_t)T * 3072 * 2;
  u16* kvb  = (u16*)(wsb + off); off += (size_t)T * 4096 * 2;
  u16* at   = (u16*)(wsb + off); off += (size_t)T * 2048 * 2;
  u16* vt   = xb;   // reuse: xb dead after GEMM 1; same size (T*2048)

  // 0) all repacks in one dispatch
  repack_all_k<<<dim3(8192, 5), 256, 0, stream>>>(
      x, wq_a, wkv_a, wq_b, wkv_b, wo, xb, wcat, wqbb, wkbb, wob);

  // 1) qkv = xb @ [wq_a;wkv_a;pad]^T   [T,2304]  (qa | kv | kpe | pad)
  gemm256_k<0><<<dim3(2304 / 256, T / 256), 512, 0, stream>>>(xb, 2048, wcat, 2048, qkv, 2304, 2048);
  // 2) fused: rmsnorm(qa), rmsnorm(kv), rope(kpe)
  normrope_k<<<T, 256, 0, stream>>>(qkv, qnw, kvnw, cosb, sinb, S);
  // 3) merged: qf = qa @ wq_b^T [T,3072] (+ fused q-RoPE on accumulator)
  //    AND kvb = kv @ wkv_b^T [T,4096] (V half written transposed to vt;
  //    vt overlays dead xb; dual reads only qkv/wqbb/wkbb -> no hazard)
  gemm256_dual<<<dim3(3072 / 256 + 4096 / 256, T / 256), 512, 0, stream>>>(
      qkv, 2304, wqbb, 1536, qf, 3072, 1536, 3072 / 256,
      qkv + 1536, 2304, wkbb, 512, kvb, 4096, 512,
      cosb, sinb, S - 1, vt);
  // 4) MFMA flash attention (paired q-tiles, XCD-grouped, r3 schedule)
  //    [vtrans dispatch eliminated: V arrives pre-transposed from step 3]
  attn_mfma<<<dim3((S / 128) * 32), 256, 0, stream>>>(qf, kvb, qkv + 2048, 2304, vt, at, S);
  // 5) out = at @ wo^T [T,2048] fp32
  gemm256_k<1><<<dim3(2048 / 256, T / 256), 512, 0, stream>>>(at, 2048, wob, 2048, out, 2048, 2048);
}